// Round 1
// baseline (108.760 us; speedup 1.0000x reference)
//
#include <hip/hip_runtime.h>
#include <math.h>

#define N 32
#define B 4
#define EMB 512
#define FEAT 512
#define NDO 496           // N*(N-1)/2
#define BDO (B*NDO)       // 1984

// ---- output offsets (floats) ----
#define OFF_XRAW  ((size_t)0)
#define OFF_XDO   ((size_t)(B*N*FEAT))                       // 65536
#define OFF_LABEL (OFF_XDO + (size_t)BDO*N*FEAT)             // 32571392
#define OFF_CG    (OFF_LABEL + (size_t)BDO*N*N)              // 34603008
#define OFF_E     (OFF_CG + (size_t)B*N*N)                   // 34607104
#define OFF_S     (OFF_E + (size_t)B*N*N)                    // 34611200

// ---- workspace offsets (floats) ----
#define WS_FEAT   0
#define WS_SRC    (WS_FEAT + B*N*FEAT)      // 65536
#define WS_DST    (WS_SRC + B*N)            // 65664
#define WS_ATTN   (WS_DST + B*N)            // 65792
#define WS_W      (WS_ATTN + B*N*N)         // 69888
#define WS_FU     (WS_W + B*N*N)            // 73984
#define WS_FEAT2  (WS_FU + B*N*FEAT)        // 139520
#define WS_POS    (WS_FEAT2 + B*N*FEAT)     // 205056 (as u32)
#define WS_COM    (WS_POS + B*N)            // 205184 (as u32)

// ---------------------------------------------------------------------------
// K1/K3: out[row, :] = X[row, :] @ Wt  (512x512), optional src/dst reductions
// grid = B*N (128), block = 128 (4 cols/thread, float4)
// ---------------------------------------------------------------------------
template<bool WITH_ATT>
__global__ __launch_bounds__(128) void rowgemm_kernel(
    const float* __restrict__ X, const float* __restrict__ Wt,
    float* __restrict__ out,
    const float* __restrict__ a_src, const float* __restrict__ a_dst,
    float* __restrict__ src_out, float* __restrict__ dst_out)
{
    __shared__ float xrow[512];
    __shared__ float red[2][2];
    const int row = blockIdx.x;
    const int tid = threadIdx.x;
    reinterpret_cast<float4*>(xrow)[tid] =
        reinterpret_cast<const float4*>(X + (size_t)row * 512)[tid];
    __syncthreads();
    const int c = tid * 4;
    float a0 = 0.f, a1 = 0.f, a2 = 0.f, a3 = 0.f;
    for (int k = 0; k < 512; ++k) {
        const float hv = xrow[k];
        const float4 w = *reinterpret_cast<const float4*>(Wt + (size_t)k * 512 + c);
        a0 = fmaf(hv, w.x, a0); a1 = fmaf(hv, w.y, a1);
        a2 = fmaf(hv, w.z, a2); a3 = fmaf(hv, w.w, a3);
    }
    *reinterpret_cast<float4*>(out + (size_t)row * 512 + c) = make_float4(a0, a1, a2, a3);
    if (WITH_ATT) {
        const float4 as = *reinterpret_cast<const float4*>(a_src + c);
        const float4 ad = *reinterpret_cast<const float4*>(a_dst + c);
        float ps = a0 * as.x + a1 * as.y + a2 * as.z + a3 * as.w;
        float pd = a0 * ad.x + a1 * ad.y + a2 * ad.z + a3 * ad.w;
        #pragma unroll
        for (int off = 32; off > 0; off >>= 1) {
            ps += __shfl_down(ps, off);
            pd += __shfl_down(pd, off);
        }
        const int wave = tid >> 6;
        if ((tid & 63) == 0) { red[wave][0] = ps; red[wave][1] = pd; }
        __syncthreads();
        if (tid == 0) {
            src_out[row] = red[0][0] + red[1][0];
            dst_out[row] = red[0][1] + red[1][1];
        }
    }
}

// ---------------------------------------------------------------------------
// K2: per-batch: softmax->attn, pos/common bits, inv(I-attn), e/s/W, fU
// grid = B (4), block = 256
// ---------------------------------------------------------------------------
__global__ __launch_bounds__(256) void batch_kernel(
    const float* __restrict__ adj, const float* __restrict__ featp,
    const float* __restrict__ srcp, const float* __restrict__ dstp,
    const float* __restrict__ fce_w, const float* __restrict__ fce_b,
    const float* __restrict__ fcs_w, const float* __restrict__ fcs_b,
    const float* __restrict__ eps_main,
    float* __restrict__ out,
    float* __restrict__ ws_attn, float* __restrict__ ws_W,
    float* __restrict__ ws_fU,
    unsigned* __restrict__ posb, unsigned* __restrict__ comb)
{
    __shared__ float attnL[N * N];
    __shared__ float Minv[N * N];
    __shared__ float dstL[N];
    __shared__ unsigned pbits[N];
    const int b = blockIdx.x;
    const int tid = threadIdx.x;
    if (tid < N) dstL[tid] = dstp[b * N + tid];
    __syncthreads();
    if (tid < N) {
        const int i = tid;
        const float srcv = srcp[b * N + i];
        const float* arow = adj + (size_t)b * N * N + i * N;
        float sc[N];
        float mx = -3e38f;
        bool any = false;
        #pragma unroll
        for (int j = 0; j < N; ++j) {
            const bool m = (arow[j] > 0.f) && (j < i);
            float x = srcv + dstL[j];
            x = (x >= 0.f) ? x : 0.2f * x;
            sc[j] = m ? x : -3e38f;
            if (m) { any = true; mx = fmaxf(mx, x); }
        }
        float den = 0.f;
        #pragma unroll
        for (int j = 0; j < N; ++j) {
            const float e = (sc[j] > -1e38f) ? __expf(sc[j] - mx) : 0.f;
            sc[j] = e;
            den += e;
        }
        const float inv_den = any ? (1.f / den) : 0.f;
        unsigned pb = 0;
        #pragma unroll
        for (int j = 0; j < N; ++j) {
            const float a = sc[j] * inv_den;
            attnL[i * N + j] = a;
            if (a > 0.f) pb |= (1u << j);
        }
        pbits[i] = pb;
        posb[b * N + i] = pb;
    }
    __syncthreads();
    // copy attn -> causal_graph out + ws
    for (int idx = tid; idx < N * N; idx += 256) {
        const float a = attnL[idx];
        out[OFF_CG + (size_t)b * N * N + idx] = a;
        ws_attn[b * N * N + idx] = a;
    }
    if (tid < N) {
        const unsigned my = pbits[tid];
        unsigned cb = 0;
        #pragma unroll
        for (int j = 0; j < N; ++j) if (my & pbits[j]) cb |= (1u << j);
        comb[b * N + tid] = cb;
    }
    // inversion of (I - attn): column j per lane, forward substitution
    if (tid < N) {
        const int j = tid;
        float x[N];
        #pragma unroll
        for (int i = 0; i < N; ++i) {
            float s = (i == j) ? 1.f : 0.f;
            #pragma unroll
            for (int k = 0; k < N; ++k)
                if (k < i) s = fmaf(attnL[i * N + k], x[k], s);
            x[i] = s;
            Minv[i * N + j] = s;
        }
    }
    __syncthreads();
    // e, s, W
    const float few = fce_w[0], feb = fce_b[0], fsw = fcs_w[0], fsb = fcs_b[0];
    for (int idx = tid; idx < N * N; idx += 256) {
        const float m = Minv[idx];
        const float e = fmaf(few, m, feb);
        const float s2 = fmaf(fsw, m, fsb);
        out[OFF_E + (size_t)b * N * N + idx] = e;
        out[OFF_S + (size_t)b * N * N + idx] = s2;
        ws_W[b * N * N + idx] = (m == 0.f) ? 0.f
            : fmaf(__expf(0.5f * s2), eps_main[b * N * N + idx], e);
    }
    // fU = relu(attn @ feat)  (attn strictly lower-triangular)
    const int c = 2 * tid;
    float2 v[N];
    #pragma unroll
    for (int j = 0; j < N; ++j)
        v[j] = *reinterpret_cast<const float2*>(&featp[(size_t)(b * N + j) * FEAT + c]);
    #pragma unroll
    for (int i = 0; i < N; ++i) {
        float s0 = 0.f, s1 = 0.f;
        #pragma unroll
        for (int j4 = 0; j4 < 8; ++j4) {
            if (4 * j4 < i) {
                const float4 w = *reinterpret_cast<const float4*>(&attnL[i * N + 4 * j4]);
                s0 = fmaf(w.x, v[4*j4+0].x, s0); s1 = fmaf(w.x, v[4*j4+0].y, s1);
                s0 = fmaf(w.y, v[4*j4+1].x, s0); s1 = fmaf(w.y, v[4*j4+1].y, s1);
                s0 = fmaf(w.z, v[4*j4+2].x, s0); s1 = fmaf(w.z, v[4*j4+2].y, s1);
                s0 = fmaf(w.w, v[4*j4+3].x, s0); s1 = fmaf(w.w, v[4*j4+3].y, s1);
            }
        }
        *reinterpret_cast<float2*>(&ws_fU[(size_t)(b * N + i) * FEAT + c]) =
            make_float2(fmaxf(s0, 0.f), fmaxf(s1, 0.f));
    }
}

// ---------------------------------------------------------------------------
// K3b: X_raw[b,i,:] = relu(W[b,i,:] @ feat2[b])  grid = B*N, block = 128
// ---------------------------------------------------------------------------
__global__ __launch_bounds__(128) void xraw_kernel(
    const float* __restrict__ ws_W, const float* __restrict__ ws_feat2,
    float* __restrict__ out)
{
    const int row = blockIdx.x;
    const int b = row >> 5, i = row & 31;
    __shared__ float Wrow[N];
    const int tid = threadIdx.x;
    if (tid < N) Wrow[tid] = ws_W[(size_t)b * N * N + i * N + tid];
    __syncthreads();
    const int c = 4 * tid;
    float4 acc = make_float4(0.f, 0.f, 0.f, 0.f);
    #pragma unroll
    for (int j = 0; j < N; ++j) {
        const float w = Wrow[j];
        const float4 f = *reinterpret_cast<const float4*>(&ws_feat2[(size_t)(b * N + j) * FEAT + c]);
        acc.x = fmaf(w, f.x, acc.x); acc.y = fmaf(w, f.y, acc.y);
        acc.z = fmaf(w, f.z, acc.z); acc.w = fmaf(w, f.w, acc.w);
    }
    *reinterpret_cast<float4*>(&out[OFF_XRAW + (size_t)row * FEAT + c]) =
        make_float4(fmaxf(acc.x, 0.f), fmaxf(acc.y, 0.f), fmaxf(acc.z, 0.f), fmaxf(acc.w, 0.f));
}

// ---------------------------------------------------------------------------
// K4: per (b, pair): invert I+attn' (rows a,b zeroed), W_do, label, X_do
// grid = BDO (1984), block = 256
// ---------------------------------------------------------------------------
__global__ __launch_bounds__(256) void do_kernel(
    const float* __restrict__ ws_attn, const float* __restrict__ ws_feat2,
    const unsigned* __restrict__ posb, const unsigned* __restrict__ comb,
    const float* __restrict__ fce_w, const float* __restrict__ fce_b,
    const float* __restrict__ fcs_w, const float* __restrict__ fcs_b,
    const float* __restrict__ eps_do,
    float* __restrict__ out)
{
    __shared__ float L[N * N];
    __shared__ float Minv[N * N];
    __shared__ float Wd[N * N];
    const int p = blockIdx.x;
    const int b = p / NDO;
    int tt = p - b * NDO;
    int ai = 0, rem = N - 1;
    while (tt >= rem) { tt -= rem; ++ai; --rem; }
    const int bi = ai + 1 + tt;
    const int tid = threadIdx.x;
    // load attn with rows ai, bi zeroed
    for (int idx = tid; idx < N * N; idx += 256) {
        const int i = idx >> 5;
        const float vv = ws_attn[b * N * N + idx];
        L[idx] = (i == ai || i == bi) ? 0.f : vv;
    }
    // register-cache feat2 columns (L2-hot; no LDS staging needed)
    const int c = 2 * tid;
    float2 v[N];
    #pragma unroll
    for (int j = 0; j < N; ++j)
        v[j] = *reinterpret_cast<const float2*>(&ws_feat2[(size_t)(b * N + j) * FEAT + c]);
    __syncthreads();
    // inversion of (I + L): column j per lane
    if (tid < N) {
        const int j = tid;
        float x[N];
        #pragma unroll
        for (int i = 0; i < N; ++i) {
            float s = (i == j) ? 1.f : 0.f;
            #pragma unroll
            for (int k = 0; k < N; ++k)
                if (k < i) s = fmaf(-L[i * N + k], x[k], s);
            x[i] = s;
            Minv[i * N + j] = s;
        }
    }
    __syncthreads();
    // W_do into LDS + label out
    const float few = fce_w[0], feb = fce_b[0], fsw = fcs_w[0], fsb = fcs_b[0];
    for (int idx = tid; idx < N * N; idx += 256) {
        const int i = idx >> 5, j = idx & 31;
        const float m = Minv[idx];
        const float e = fmaf(few, m, feb);
        const float s2 = fmaf(fsw, m, fsb);
        Wd[idx] = (m == 0.f) ? 0.f
            : fmaf(__expf(0.5f * s2), eps_do[(size_t)p * N * N + idx], e);
        const bool lower = i > j;
        const bool c23 = lower && (((j == ai) && (i != bi)) || ((j == bi) && (i != ai)));
        const bool c4 = lower && (i != ai) && (i != bi) && (j != ai) && (j != bi);
        const bool pos = (posb[b * N + i] >> j) & 1u;
        const bool com = (comb[b * N + i] >> j) & 1u;
        const bool lab = (i == j) || (c23 && pos) || (c4 && com);
        out[OFF_LABEL + (size_t)p * N * N + idx] = lab ? 1.f : 0.f;
    }
    __syncthreads();
    // X_do = relu(Wd @ feat2[b])   (Wd lower-triangular incl. diagonal)
    float* Xdo = out + OFF_XDO + (size_t)p * N * FEAT;
    #pragma unroll
    for (int i = 0; i < N; ++i) {
        float s0 = 0.f, s1 = 0.f;
        #pragma unroll
        for (int j4 = 0; j4 < 8; ++j4) {
            if (4 * j4 <= i) {
                const float4 w = *reinterpret_cast<const float4*>(&Wd[i * N + 4 * j4]);
                s0 = fmaf(w.x, v[4*j4+0].x, s0); s1 = fmaf(w.x, v[4*j4+0].y, s1);
                s0 = fmaf(w.y, v[4*j4+1].x, s0); s1 = fmaf(w.y, v[4*j4+1].y, s1);
                s0 = fmaf(w.z, v[4*j4+2].x, s0); s1 = fmaf(w.z, v[4*j4+2].y, s1);
                s0 = fmaf(w.w, v[4*j4+3].x, s0); s1 = fmaf(w.w, v[4*j4+3].y, s1);
            }
        }
        *reinterpret_cast<float2*>(&Xdo[(size_t)i * FEAT + c]) =
            make_float2(fmaxf(s0, 0.f), fmaxf(s1, 0.f));
    }
}

// ---------------------------------------------------------------------------
extern "C" void kernel_launch(void* const* d_in, const int* in_sizes, int n_in,
                              void* d_out, int out_size, void* d_ws, size_t ws_size,
                              hipStream_t stream)
{
    const float* h        = (const float*)d_in[0];
    const float* adj      = (const float*)d_in[1];
    const float* enc_Wt   = (const float*)d_in[3];
    const float* a_src    = (const float*)d_in[4];
    const float* a_dst    = (const float*)d_in[5];
    const float* dec_Wt   = (const float*)d_in[6];
    const float* fce_w    = (const float*)d_in[7];
    const float* fce_b    = (const float*)d_in[8];
    const float* fcs_w    = (const float*)d_in[9];
    const float* fcs_b    = (const float*)d_in[10];
    const float* eps_main = (const float*)d_in[11];
    const float* eps_do   = (const float*)d_in[12];
    float* out = (float*)d_out;
    float* ws  = (float*)d_ws;

    float* ws_feat  = ws + WS_FEAT;
    float* ws_src   = ws + WS_SRC;
    float* ws_dst   = ws + WS_DST;
    float* ws_attn  = ws + WS_ATTN;
    float* ws_W     = ws + WS_W;
    float* ws_fU    = ws + WS_FU;
    float* ws_feat2 = ws + WS_FEAT2;
    unsigned* ws_pos = (unsigned*)(ws + WS_POS);
    unsigned* ws_com = (unsigned*)(ws + WS_COM);

    // K1: feat = h @ enc_Wt, src/dst
    rowgemm_kernel<true><<<B * N, 128, 0, stream>>>(
        h, enc_Wt, ws_feat, a_src, a_dst, ws_src, ws_dst);
    // K2: attn, inv, e/s/W, fU, pos/common
    batch_kernel<<<B, 256, 0, stream>>>(
        adj, ws_feat, ws_src, ws_dst, fce_w, fce_b, fcs_w, fcs_b,
        eps_main, out, ws_attn, ws_W, ws_fU, ws_pos, ws_com);
    // K3: feat2 = fU @ dec_Wt
    rowgemm_kernel<false><<<B * N, 128, 0, stream>>>(
        ws_fU, dec_Wt, ws_feat2, nullptr, nullptr, nullptr, nullptr);
    // K3b: X_raw
    xraw_kernel<<<B * N, 128, 0, stream>>>(ws_W, ws_feat2, out);
    // K4: label + X_do
    do_kernel<<<BDO, 256, 0, stream>>>(
        ws_attn, ws_feat2, ws_pos, ws_com, fce_w, fce_b, fcs_w, fcs_b,
        eps_do, out);
}